// Round 12
// baseline (535.624 us; speedup 1.0000x reference)
//
#include <hip/hip_runtime.h>
#include <math.h>

#define NBF 4104             // B*F = 8*513
#define XT_FLOATS 16809984   // 8*513*8*512

// Static device scratch; fully overwritten before read each call -> deterministic.
__device__ float d_partials[NBF];
__device__ float d_scales[8];

// Phase-A macros, parameterized on register-set names (ping-pong A/B).
// All accumulators/buffers are PLAIN LOCALS with compile-time indices.
#define PA_CROSS(P,N,C,XR,XI) cr[P] += ar*XR[N].C + ai*XI[N].C; \
                              ci[P] += ai*XR[N].C - ar*XI[N].C;

#define PA_G0(C,XR,XI,RV) { const float rw = fmaxf(RV.C, 1e-3f); float ar, ai;  \
    ar = rw*XR[0].C; ai = rw*XI[0].C; d0 += ar*XR[0].C + ai*XI[0].C;            \
    PA_CROSS(0,1,C,XR,XI) PA_CROSS(1,2,C,XR,XI) PA_CROSS(2,3,C,XR,XI)           \
    PA_CROSS(3,4,C,XR,XI) PA_CROSS(4,5,C,XR,XI) PA_CROSS(5,6,C,XR,XI)           \
    PA_CROSS(6,7,C,XR,XI)                                                       \
    ar = rw*XR[7].C; ai = rw*XI[7].C; d1 += ar*XR[7].C + ai*XI[7].C; }

#define PA_G1(C,XR,XI,RV) { const float rw = fmaxf(RV.C, 1e-3f); float ar, ai;  \
    ar = rw*XR[1].C; ai = rw*XI[1].C; d0 += ar*XR[1].C + ai*XI[1].C;            \
    PA_CROSS(0,2,C,XR,XI) PA_CROSS(1,3,C,XR,XI) PA_CROSS(2,4,C,XR,XI)           \
    PA_CROSS(3,5,C,XR,XI) PA_CROSS(4,6,C,XR,XI) PA_CROSS(5,7,C,XR,XI)           \
    ar = rw*XR[6].C; ai = rw*XI[6].C; d1 += ar*XR[6].C + ai*XI[6].C;            \
    PA_CROSS(6,7,C,XR,XI) }

#define PA_G2(C,XR,XI,RV) { const float rw = fmaxf(RV.C, 1e-3f); float ar, ai;  \
    ar = rw*XR[2].C; ai = rw*XI[2].C; d0 += ar*XR[2].C + ai*XI[2].C;            \
    PA_CROSS(0,3,C,XR,XI) PA_CROSS(1,4,C,XR,XI) PA_CROSS(2,5,C,XR,XI)           \
    PA_CROSS(3,6,C,XR,XI) PA_CROSS(4,7,C,XR,XI)                                 \
    ar = rw*XR[5].C; ai = rw*XI[5].C; d1 += ar*XR[5].C + ai*XI[5].C;            \
    PA_CROSS(5,6,C,XR,XI) PA_CROSS(6,7,C,XR,XI) }

#define PA_G3(C,XR,XI,RV) { const float rw = fmaxf(RV.C, 1e-3f); float ar, ai;  \
    ar = rw*XR[3].C; ai = rw*XI[3].C; d0 += ar*XR[3].C + ai*XI[3].C;            \
    PA_CROSS(0,4,C,XR,XI) PA_CROSS(1,5,C,XR,XI) PA_CROSS(2,6,C,XR,XI)           \
    PA_CROSS(3,7,C,XR,XI)                                                       \
    ar = rw*XR[4].C; ai = rw*XI[4].C; d1 += ar*XR[4].C + ai*XI[4].C;            \
    PA_CROSS(4,5,C,XR,XI) PA_CROSS(5,6,C,XR,XI) PA_CROSS(6,7,C,XR,XI) }

#define PA_CALC(XR,XI,RV)                                      \
    if      (g == 0) { PA_G0(x,XR,XI,RV) PA_G0(y,XR,XI,RV) }   \
    else if (g == 1) { PA_G1(x,XR,XI,RV) PA_G1(y,XR,XI,RV) }   \
    else if (g == 2) { PA_G2(x,XR,XI,RV) PA_G2(y,XR,XI,RV) }   \
    else             { PA_G3(x,XR,XI,RV) PA_G3(y,XR,XI,RV) }

#define PA_LOAD(I,XR,XI,RV) { const int t_ = ((I) << 4) + (tl << 1);  \
    RV = *(const float2*)&rrow[t_];                                   \
    for (int n_ = 0; n_ < 8; ++n_) {                                  \
        XR[n_] = *(const float2*)&xre[(n_ << 9) + t_];                \
        XI[n_] = *(const float2*)&xim[(n_ << 9) + t_]; } }

#define VSTD2(D,M)  s_V[k][M][M] = make_float2((D)*invT, 0.f);
#define VSTO2(P,M,N){ const float vr=cr[P]*invT, vi=ci[P]*invT;  \
                      s_V[k][M][N] = make_float2(vr,  vi);       \
                      s_V[k][N][M] = make_float2(vr, -vi); }

// launch_bounds law (empirical): VGPR cap = 256/arg2. arg2=2 -> 128.
// r11 (cap 85, 42% occ) proved occupancy is NOT the lever: VALUBusy stuck at 36%
// because loads can't be hoisted under the reg cap. This round: 2-deep register
// ping-pong (live ~95 <= 128 cap) so every load has a full 72-FLOP body before
// first use -> latency hidden per-wave.
__global__ __launch_bounds__(256, 2) void iss_main(
    const float* __restrict__ g_r,
    const float* __restrict__ g_xre,
    const float* __restrict__ g_xim,
    const float* __restrict__ g_Qre,
    const float* __restrict__ g_Qim,
    float* __restrict__ g_out,
    const int qmode,        // 2 = interleaved re,im pairs; 1 = real part only
    const int xt_off)       // float offset where the xt region begins
{
    __shared__ float2 s_V[8][8][9];    // padded row stride
    __shared__ float2 s_Q[8][8];
    __shared__ float  s_part[4];

    const int tid = threadIdx.x;
    const int bf  = blockIdx.x;
    const size_t base = (size_t)bf * 4096;

    const float* xre = g_xre + base;
    const float* xim = g_xim + base;

    if (tid < 64)
        s_Q[tid>>3][tid&7] = make_float2(g_Qre[(size_t)bf*64 + tid],
                                         g_Qim[(size_t)bf*64 + tid]);

    // ---- phase A: V[k] = (1/T) sum_t max(r,1e-3) x x^H -------------------
    // tid = (g<<6)|(k<<3)|tl : wave g owns row-pair {g,7-g}; 8 t-lanes per (g,k).
    const int tl = tid & 7;
    const int k  = (tid >> 3) & 7;
    const int g  = tid >> 6;          // wave index, uniform

    float d0 = 0.f, d1 = 0.f;
    float cr[7], ci[7];
    #pragma unroll
    for (int p = 0; p < 7; ++p) { cr[p] = 0.f; ci[p] = 0.f; }

    {
        const float* rrow = g_r + base + (k << 9);
        float2 xrA[8], xiA[8], rvA;
        float2 xrB[8], xiB[8], rvB;
        PA_LOAD(0, xrA, xiA, rvA)
        #pragma unroll
        for (int i = 0; i < 32; i += 2) {
            PA_LOAD(i + 1, xrB, xiB, rvB)     // issue B loads BEFORE computing A
            PA_CALC(xrA, xiA, rvA)            // 72 VALU covers B's load latency
            if (i + 2 < 32) PA_LOAD(i + 2, xrA, xiA, rvA)
            PA_CALC(xrB, xiB, rvB)
        }
    }

    // reduce across the 8 t-lanes of each (g,k): xor 1,2,4 stay in-group
    #pragma unroll
    for (int off = 1; off < 8; off <<= 1) {
        d0 += __shfl_xor(d0, off, 64);
        d1 += __shfl_xor(d1, off, 64);
        #pragma unroll
        for (int p = 0; p < 7; ++p) {
            cr[p] += __shfl_xor(cr[p], off, 64);
            ci[p] += __shfl_xor(ci[p], off, 64);
        }
    }

    if (tl == 0) {
        const float invT = 1.0f / 512.0f;
        if (g == 0) {
            VSTD2(d0,0) VSTO2(0,0,1) VSTO2(1,0,2) VSTO2(2,0,3) VSTO2(3,0,4)
                        VSTO2(4,0,5) VSTO2(5,0,6) VSTO2(6,0,7)
            VSTD2(d1,7)
        } else if (g == 1) {
            VSTD2(d0,1) VSTO2(0,1,2) VSTO2(1,1,3) VSTO2(2,1,4) VSTO2(3,1,5)
                        VSTO2(4,1,6) VSTO2(5,1,7)
            VSTD2(d1,6) VSTO2(6,6,7)
        } else if (g == 2) {
            VSTD2(d0,2) VSTO2(0,2,3) VSTO2(1,2,4) VSTO2(2,2,5) VSTO2(3,2,6)
                        VSTO2(4,2,7)
            VSTD2(d1,5) VSTO2(5,5,6) VSTO2(6,5,7)
        } else {
            VSTD2(d0,3) VSTO2(0,3,4) VSTO2(1,3,5) VSTO2(2,3,6) VSTO2(3,3,7)
            VSTD2(d1,4) VSTO2(4,4,5) VSTO2(5,4,6) VSTO2(6,4,7)
        }
    }
    __syncthreads();

    // ---- diag fix + phase B: SINGLE WAVE ----
    if (tid < 64) {
        {
            const int kq = tid >> 3, mq = tid & 7;
            const float dv = s_V[kq][mq][mq].x;
            float tr = dv;
            #pragma unroll
            for (int off = 1; off < 8; off <<= 1) tr += __shfl_xor(tr, off, 64);
            s_V[kq][mq][mq].x = dv + fmaxf(tr, 1.0f) * 1e-6f;
        }
        const int kp = tid >> 3, mm = tid & 7;
        float vRr[8], vRi[8];
        #pragma unroll
        for (int n = 0; n < 8; ++n) {
            const float2 V = s_V[kp][mm][n];
            vRr[n] = V.x; vRi[n] = V.y;
        }
        const float2 Q0 = s_Q[kp][mm];
        float qre = Q0.x, qim = Q0.y;

        #pragma unroll
        for (int step = 0; step < 16; ++step) {
            const int kk = step & 7;
            float qnr[8], qni[8];
            #pragma unroll
            for (int n = 0; n < 8; ++n) {
                qnr[n] = __shfl(qre, (kk<<3)+n, 64);
                qni[n] = __shfl(qim, (kk<<3)+n, 64);
            }
            const float qmr = __shfl(qre, (kk<<3)+mm, 64);
            const float qmi = __shfl(qim, (kk<<3)+mm, 64);

            float vqr = 0.f, vqi = 0.f;
            #pragma unroll
            for (int n = 0; n < 8; ++n) {
                vqr += vRr[n]*qnr[n] + vRi[n]*qni[n];   // V * conj(q)
                vqi += vRi[n]*qnr[n] - vRr[n]*qni[n];
            }
            float p   = qmr*vqr - qmi*vqi;              // Re(q_m * Vq_m)
            float tre = qre*vqr - qim*vqi;              // Q_own * Vq_own
            float tim = qre*vqi + qim*vqr;
            #pragma unroll
            for (int off = 1; off < 8; off <<= 1) {
                p   += __shfl_xor(p,   off, 64);
                tre += __shfl_xor(tre, off, 64);
                tim += __shfl_xor(tim, off, 64);
            }
            const float qvq = fmaxf(p, 1e-6f);
            float vr_, vi_;
            if (kp == kk) { vr_ = 1.0f - rsqrtf(qvq); vi_ = 0.f; }
            else { const float inv = 1.0f / qvq; vr_ = tre*inv; vi_ = tim*inv; }
            qre -= vr_*qmr - vi_*qmi;
            qim -= vr_*qmi + vi_*qmr;
        }

        s_Q[kp][mm] = make_float2(qre, qim);
        if (qmode == 2) {
            g_out[(size_t)bf*128 + tid*2]     = qre;
            g_out[(size_t)bf*128 + tid*2 + 1] = qim;
        } else {
            g_out[(size_t)bf*64 + tid] = qre;
        }
    }
    __syncthreads();

    // ---- phase C: xt = |Q x|^2, t-major from GLOBAL (L1/L2-hot after phase A),
    //      float2 loads + float2 stores, fully coalesced ----
    float lsum = 0.f;
    float* out_xt = g_out + xt_off;
    {
        const int t0 = tid << 1;              // thread owns t = {2tid, 2tid+1}
        float2 xr2[8], xi2[8];
        #pragma unroll
        for (int n = 0; n < 8; ++n) {
            xr2[n] = *(const float2*)&xre[(n << 9) + t0];
            xi2[n] = *(const float2*)&xim[(n << 9) + t0];
        }
        #pragma unroll
        for (int m = 0; m < 8; ++m) {
            float2 qv[8];
            #pragma unroll
            for (int n = 0; n < 8; ++n) qv[n] = s_Q[m][n];   // broadcast (free)
            float ar = 0.f, ai = 0.f, br = 0.f, bi = 0.f;
            #pragma unroll
            for (int n = 0; n < 8; ++n) {
                ar += qv[n].x*xr2[n].x - qv[n].y*xi2[n].x;
                ai += qv[n].x*xi2[n].x + qv[n].y*xr2[n].x;
                br += qv[n].x*xr2[n].y - qv[n].y*xi2[n].y;
                bi += qv[n].x*xi2[n].y + qv[n].y*xr2[n].y;
            }
            float2 pw;
            pw.x = ar*ar + ai*ai;
            pw.y = br*br + bi*bi;
            *(float2*)&out_xt[base + (m << 9) + t0] = pw;
            lsum += pw.x + pw.y;
        }
    }
    #pragma unroll
    for (int off = 32; off >= 1; off >>= 1) lsum += __shfl_xor(lsum, off, 64);
    if ((tid & 63) == 0) s_part[tid >> 6] = lsum;
    __syncthreads();
    if (tid == 0) d_partials[bf] = s_part[0] + s_part[1] + s_part[2] + s_part[3];
}

__global__ __launch_bounds__(256) void iss_scale()
{
    const int b = blockIdx.x, tid = threadIdx.x;
    __shared__ float sp[4];
    float s = 0.f;
    for (int i = tid; i < 513; i += 256) s += d_partials[b*513 + i];
    #pragma unroll
    for (int off = 32; off >= 1; off >>= 1) s += __shfl_xor(s, off, 64);
    if ((tid & 63) == 0) sp[tid >> 6] = s;
    __syncthreads();
    if (tid == 0) d_scales[b] = (sp[0]+sp[1]+sp[2]+sp[3]) / (513.0f * 8.0f * 512.0f);
}

__global__ __launch_bounds__(256) void iss_norm(
    float* __restrict__ g_out,
    const int nq4,     // Q region in float4s  (= xt_off/4)
    const int qb4,     // float4s per batch in Q region
    const int nt4)     // total float4s (= out_size/4)
{
    float4* o4 = (float4*)g_out;
    for (int i = blockIdx.x*256 + threadIdx.x; i < nt4; i += gridDim.x*256) {
        float s;
        if (i < nq4) {
            const int b = i / qb4;
            s = rsqrtf(fmaxf(d_scales[b], 1e-6f));
        } else {
            const int j = i - nq4;
            const int b = j / 525312;          // xt float4s per batch
            s = 1.0f / d_scales[b];
        }
        float4 v = o4[i];
        v.x *= s; v.y *= s; v.z *= s; v.w *= s;
        o4[i] = v;
    }
}

extern "C" void kernel_launch(void* const* d_in, const int* in_sizes, int n_in,
                              void* d_out, int out_size, void* d_ws, size_t ws_size,
                              hipStream_t stream) {
    const float* r   = (const float*)d_in[0];
    const float* xre = (const float*)d_in[1];
    const float* xim = (const float*)d_in[2];
    const float* Qre = (const float*)d_in[3];
    const float* Qim = (const float*)d_in[4];
    float* out = (float*)d_out;

    const int q_floats = out_size - XT_FLOATS;
    const int qmode  = (q_floats >= 525312) ? 2 : 1;
    const int xt_off = (qmode == 2) ? 525312 : 262656;
    const int nq4 = xt_off / 4;
    const int qb4 = xt_off / (4 * 8);
    const int nt4 = nq4 + XT_FLOATS / 4;

    iss_main <<<NBF, 256, 0, stream>>>(r, xre, xim, Qre, Qim, out, qmode, xt_off);
    iss_scale<<<8,   256, 0, stream>>>();
    iss_norm <<<4096,256, 0, stream>>>(out, nq4, qb4, nt4);
}

// Round 14
// 305.104 us; speedup vs baseline: 1.7555x; 1.7555x over previous
//
#include <hip/hip_runtime.h>
#include <math.h>

#define NBF 4104             // B*F = 8*513
#define XT_FLOATS 16809984   // 8*513*8*512

// Static device scratch; fully overwritten before read each call -> deterministic.
__device__ float  d_partials[NBF];
__device__ float  d_scales[8];
__device__ float2 d_Qc[NBF * 64];   // full complex Q (g_out only holds Re in qmode=1)

// Phase-A macros (r11 form — compiler-scheduled; manual ping-pong loses, r12).
#define PA_CROSS(P,N,C) cr[P] += ar*xr2[N].C + ai*xi2[N].C; \
                        ci[P] += ai*xr2[N].C - ar*xi2[N].C;

#define PA_G0(C) { const float rw = fmaxf(rv.C, 1e-3f); float ar, ai;          \
    ar = rw*xr2[0].C; ai = rw*xi2[0].C; d0 += ar*xr2[0].C + ai*xi2[0].C;       \
    PA_CROSS(0,1,C) PA_CROSS(1,2,C) PA_CROSS(2,3,C) PA_CROSS(3,4,C)            \
    PA_CROSS(4,5,C) PA_CROSS(5,6,C) PA_CROSS(6,7,C)                            \
    ar = rw*xr2[7].C; ai = rw*xi2[7].C; d1 += ar*xr2[7].C + ai*xi2[7].C; }

#define PA_G1(C) { const float rw = fmaxf(rv.C, 1e-3f); float ar, ai;          \
    ar = rw*xr2[1].C; ai = rw*xi2[1].C; d0 += ar*xr2[1].C + ai*xi2[1].C;       \
    PA_CROSS(0,2,C) PA_CROSS(1,3,C) PA_CROSS(2,4,C) PA_CROSS(3,5,C)            \
    PA_CROSS(4,6,C) PA_CROSS(5,7,C)                                            \
    ar = rw*xr2[6].C; ai = rw*xi2[6].C; d1 += ar*xr2[6].C + ai*xi2[6].C;       \
    PA_CROSS(6,7,C) }

#define PA_G2(C) { const float rw = fmaxf(rv.C, 1e-3f); float ar, ai;          \
    ar = rw*xr2[2].C; ai = rw*xi2[2].C; d0 += ar*xr2[2].C + ai*xi2[2].C;       \
    PA_CROSS(0,3,C) PA_CROSS(1,4,C) PA_CROSS(2,5,C) PA_CROSS(3,6,C)            \
    PA_CROSS(4,7,C)                                                            \
    ar = rw*xr2[5].C; ai = rw*xi2[5].C; d1 += ar*xr2[5].C + ai*xi2[5].C;       \
    PA_CROSS(5,6,C) PA_CROSS(6,7,C) }

#define PA_G3(C) { const float rw = fmaxf(rv.C, 1e-3f); float ar, ai;          \
    ar = rw*xr2[3].C; ai = rw*xi2[3].C; d0 += ar*xr2[3].C + ai*xi2[3].C;       \
    PA_CROSS(0,4,C) PA_CROSS(1,5,C) PA_CROSS(2,6,C) PA_CROSS(3,7,C)            \
    ar = rw*xr2[4].C; ai = rw*xi2[4].C; d1 += ar*xr2[4].C + ai*xi2[4].C;       \
    PA_CROSS(4,5,C) PA_CROSS(5,6,C) PA_CROSS(6,7,C) }

#define VSTD2(D,M)  s_V[k][M][M] = make_float2((D)*invT, 0.f);
#define VSTO2(P,M,N){ const float vr=cr[P]*invT, vi=ci[P]*invT;  \
                      s_V[k][M][N] = make_float2(vr,  vi);       \
                      s_V[k][N][M] = make_float2(vr, -vi); }

__global__ __launch_bounds__(256, 3) void iss_cov(
    const float* __restrict__ g_r,
    const float* __restrict__ g_xre,
    const float* __restrict__ g_xim,
    const float* __restrict__ g_Qre,
    const float* __restrict__ g_Qim,
    float* __restrict__ g_out,
    const int qmode)
{
    __shared__ float2 s_V[8][8][9];    // padded row stride
    __shared__ float2 s_Q[8][8];

    const int tid = threadIdx.x;
    const int bf  = blockIdx.x;
    const size_t base = (size_t)bf * 4096;

    const float* xre = g_xre + base;
    const float* xim = g_xim + base;

    if (tid < 64)
        s_Q[tid>>3][tid&7] = make_float2(g_Qre[(size_t)bf*64 + tid],
                                         g_Qim[(size_t)bf*64 + tid]);

    // ---- phase A: V[k] = (1/T) sum_t max(r,1e-3) x x^H -------------------
    const int tl = tid & 7;
    const int k  = (tid >> 3) & 7;
    const int g  = tid >> 6;          // wave index, uniform

    float d0 = 0.f, d1 = 0.f;
    float cr[7], ci[7];
    #pragma unroll
    for (int p = 0; p < 7; ++p) { cr[p] = 0.f; ci[p] = 0.f; }

    {
        const float* rrow = g_r + base + (k << 9);
        #pragma unroll 4
        for (int i = 0; i < 32; ++i) {
            const int t = (i << 4) + (tl << 1);
            const float2 rv = *(const float2*)&rrow[t];
            float2 xr2[8], xi2[8];
            #pragma unroll
            for (int n = 0; n < 8; ++n) {
                xr2[n] = *(const float2*)&xre[(n << 9) + t];
                xi2[n] = *(const float2*)&xim[(n << 9) + t];
            }
            if      (g == 0) { PA_G0(x) PA_G0(y) }
            else if (g == 1) { PA_G1(x) PA_G1(y) }
            else if (g == 2) { PA_G2(x) PA_G2(y) }
            else             { PA_G3(x) PA_G3(y) }
        }
    }

    // reduce across the 8 t-lanes of each (g,k): xor 1,2,4 stay in-group
    #pragma unroll
    for (int off = 1; off < 8; off <<= 1) {
        d0 += __shfl_xor(d0, off, 64);
        d1 += __shfl_xor(d1, off, 64);
        #pragma unroll
        for (int p = 0; p < 7; ++p) {
            cr[p] += __shfl_xor(cr[p], off, 64);
            ci[p] += __shfl_xor(ci[p], off, 64);
        }
    }

    if (tl == 0) {
        const float invT = 1.0f / 512.0f;
        if (g == 0) {
            VSTD2(d0,0) VSTO2(0,0,1) VSTO2(1,0,2) VSTO2(2,0,3) VSTO2(3,0,4)
                        VSTO2(4,0,5) VSTO2(5,0,6) VSTO2(6,0,7)
            VSTD2(d1,7)
        } else if (g == 1) {
            VSTD2(d0,1) VSTO2(0,1,2) VSTO2(1,1,3) VSTO2(2,1,4) VSTO2(3,1,5)
                        VSTO2(4,1,6) VSTO2(5,1,7)
            VSTD2(d1,6) VSTO2(6,6,7)
        } else if (g == 2) {
            VSTD2(d0,2) VSTO2(0,2,3) VSTO2(1,2,4) VSTO2(2,2,5) VSTO2(3,2,6)
                        VSTO2(4,2,7)
            VSTD2(d1,5) VSTO2(5,5,6) VSTO2(6,5,7)
        } else {
            VSTD2(d0,3) VSTO2(0,3,4) VSTO2(1,3,5) VSTO2(2,3,6) VSTO2(3,3,7)
            VSTD2(d1,4) VSTO2(4,4,5) VSTO2(5,4,6) VSTO2(6,4,7)
        }
    }
    __syncthreads();

    // ---- diag fix + phase B: SINGLE WAVE, zero barriers ----
    if (tid < 64) {
        {
            const int kq = tid >> 3, mq = tid & 7;
            const float dv = s_V[kq][mq][mq].x;
            float tr = dv;
            #pragma unroll
            for (int off = 1; off < 8; off <<= 1) tr += __shfl_xor(tr, off, 64);
            s_V[kq][mq][mq].x = dv + fmaxf(tr, 1.0f) * 1e-6f;
        }
        const int kp = tid >> 3, mm = tid & 7;
        float vRr[8], vRi[8];
        #pragma unroll
        for (int n = 0; n < 8; ++n) {
            const float2 V = s_V[kp][mm][n];
            vRr[n] = V.x; vRi[n] = V.y;
        }
        const float2 Q0 = s_Q[kp][mm];
        float qre = Q0.x, qim = Q0.y;

        #pragma unroll
        for (int step = 0; step < 16; ++step) {
            const int kk = step & 7;
            float qnr[8], qni[8];
            #pragma unroll
            for (int n = 0; n < 8; ++n) {
                qnr[n] = __shfl(qre, (kk<<3)+n, 64);
                qni[n] = __shfl(qim, (kk<<3)+n, 64);
            }
            const float qmr = __shfl(qre, (kk<<3)+mm, 64);
            const float qmi = __shfl(qim, (kk<<3)+mm, 64);

            float vqr = 0.f, vqi = 0.f;
            #pragma unroll
            for (int n = 0; n < 8; ++n) {
                vqr += vRr[n]*qnr[n] + vRi[n]*qni[n];   // V * conj(q)
                vqi += vRi[n]*qnr[n] - vRr[n]*qni[n];
            }
            float p   = qmr*vqr - qmi*vqi;              // Re(q_m * Vq_m)
            float tre = qre*vqr - qim*vqi;              // Q_own * Vq_own
            float tim = qre*vqi + qim*vqr;
            #pragma unroll
            for (int off = 1; off < 8; off <<= 1) {
                p   += __shfl_xor(p,   off, 64);
                tre += __shfl_xor(tre, off, 64);
                tim += __shfl_xor(tim, off, 64);
            }
            const float qvq = fmaxf(p, 1e-6f);
            float vr_, vi_;
            if (kp == kk) { vr_ = 1.0f - rsqrtf(qvq); vi_ = 0.f; }
            else { const float inv = 1.0f / qvq; vr_ = tre*inv; vi_ = tim*inv; }
            qre -= vr_*qmr - vi_*qmi;
            qim -= vr_*qmi + vi_*qmr;
        }

        d_Qc[(size_t)bf*64 + tid] = make_float2(qre, qim);   // full complex for iss_xt
        if (qmode == 2) {
            g_out[(size_t)bf*128 + tid*2]     = qre;
            g_out[(size_t)bf*128 + tid*2 + 1] = qim;
        } else {
            g_out[(size_t)bf*64 + tid] = qre;   // harness stores Q.real only
        }
    }
}

// iss_xt: pure streaming. 128 threads per bf; thread owns 4 consecutive t
// (float4 loads of x, float4 stores of xt, coalesced); Q from d_Qc (FULL complex —
// r13 bug: reading Q back from g_out lost Im(Q) in qmode=1, xt error 6.75).
__global__ void iss_xt(
    const float* __restrict__ g_xre,
    const float* __restrict__ g_xim,
    float* __restrict__ g_out,
    const int xt_off)
{
    __shared__ float2 s_Q[8][8];
    __shared__ float  sp[2];

    const int tid = threadIdx.x;
    const int bf  = blockIdx.x;
    const size_t base = (size_t)bf * 4096;
    const float* xre = g_xre + base;
    const float* xim = g_xim + base;

    if (tid < 64)
        s_Q[tid>>3][tid&7] = d_Qc[(size_t)bf*64 + tid];
    __syncthreads();

    float* out_xt = g_out + xt_off;
    const int t0 = tid << 2;               // 4 consecutive t
    float4 xr4[8], xi4[8];
    #pragma unroll
    for (int n = 0; n < 8; ++n) {
        xr4[n] = *(const float4*)&xre[(n << 9) + t0];
        xi4[n] = *(const float4*)&xim[(n << 9) + t0];
    }
    float lsum = 0.f;
    #pragma unroll
    for (int m = 0; m < 8; ++m) {
        float2 qv[8];
        #pragma unroll
        for (int n = 0; n < 8; ++n) qv[n] = s_Q[m][n];   // broadcast (free)
        float a0=0.f,b0=0.f,a1=0.f,b1=0.f,a2=0.f,b2=0.f,a3=0.f,b3=0.f;
        #pragma unroll
        for (int n = 0; n < 8; ++n) {
            const float qr = qv[n].x, qi = qv[n].y;
            a0 += qr*xr4[n].x - qi*xi4[n].x;  b0 += qr*xi4[n].x + qi*xr4[n].x;
            a1 += qr*xr4[n].y - qi*xi4[n].y;  b1 += qr*xi4[n].y + qi*xr4[n].y;
            a2 += qr*xr4[n].z - qi*xi4[n].z;  b2 += qr*xi4[n].z + qi*xr4[n].z;
            a3 += qr*xr4[n].w - qi*xi4[n].w;  b3 += qr*xi4[n].w + qi*xr4[n].w;
        }
        float4 pw;
        pw.x = a0*a0 + b0*b0;  pw.y = a1*a1 + b1*b1;
        pw.z = a2*a2 + b2*b2;  pw.w = a3*a3 + b3*b3;
        *(float4*)&out_xt[base + (m << 9) + t0] = pw;
        lsum += pw.x + pw.y + pw.z + pw.w;
    }
    #pragma unroll
    for (int off = 32; off >= 1; off >>= 1) lsum += __shfl_xor(lsum, off, 64);
    if ((tid & 63) == 0) sp[tid >> 6] = lsum;
    __syncthreads();
    if (tid == 0) d_partials[bf] = sp[0] + sp[1];
}

__global__ __launch_bounds__(256) void iss_scale()
{
    const int b = blockIdx.x, tid = threadIdx.x;
    __shared__ float sp[4];
    float s = 0.f;
    for (int i = tid; i < 513; i += 256) s += d_partials[b*513 + i];
    #pragma unroll
    for (int off = 32; off >= 1; off >>= 1) s += __shfl_xor(s, off, 64);
    if ((tid & 63) == 0) sp[tid >> 6] = s;
    __syncthreads();
    if (tid == 0) d_scales[b] = (sp[0]+sp[1]+sp[2]+sp[3]) / (513.0f * 8.0f * 512.0f);
}

__global__ __launch_bounds__(256) void iss_norm(
    float* __restrict__ g_out,
    const int nq4,     // Q region in float4s  (= xt_off/4)
    const int qb4,     // float4s per batch in Q region
    const int nt4)     // total float4s (= out_size/4)
{
    float4* o4 = (float4*)g_out;
    for (int i = blockIdx.x*256 + threadIdx.x; i < nt4; i += gridDim.x*256) {
        float s;
        if (i < nq4) {
            const int b = i / qb4;
            s = rsqrtf(fmaxf(d_scales[b], 1e-6f));
        } else {
            const int j = i - nq4;
            const int b = j / 525312;          // xt float4s per batch
            s = 1.0f / d_scales[b];
        }
        float4 v = o4[i];
        v.x *= s; v.y *= s; v.z *= s; v.w *= s;
        o4[i] = v;
    }
}

extern "C" void kernel_launch(void* const* d_in, const int* in_sizes, int n_in,
                              void* d_out, int out_size, void* d_ws, size_t ws_size,
                              hipStream_t stream) {
    const float* r   = (const float*)d_in[0];
    const float* xre = (const float*)d_in[1];
    const float* xim = (const float*)d_in[2];
    const float* Qre = (const float*)d_in[3];
    const float* Qim = (const float*)d_in[4];
    float* out = (float*)d_out;

    const int q_floats = out_size - XT_FLOATS;
    const int qmode  = (q_floats >= 525312) ? 2 : 1;  // empirically qmode=1 (r13)
    const int xt_off = (qmode == 2) ? 525312 : 262656;
    const int nq4 = xt_off / 4;
    const int qb4 = xt_off / (4 * 8);
    const int nt4 = nq4 + XT_FLOATS / 4;

    iss_cov  <<<NBF, 256, 0, stream>>>(r, xre, xim, Qre, Qim, out, qmode);
    iss_xt   <<<NBF, 128, 0, stream>>>(xre, xim, out, xt_off);
    iss_scale<<<8,   256, 0, stream>>>();
    iss_norm <<<4096,256, 0, stream>>>(out, nq4, qb4, nt4);
}

// Round 15
// 303.366 us; speedup vs baseline: 1.7656x; 1.0057x over previous
//
#include <hip/hip_runtime.h>
#include <math.h>

#define NBF 4104             // B*F = 8*513
#define XT_FLOATS 16809984   // 8*513*8*512

// Static device scratch; fully overwritten before read each call -> deterministic.
__device__ float  d_partials[NBF];
__device__ float  d_scales[8];
__device__ float2 d_Qc[NBF * 64];   // full complex Q (g_out only holds Re in qmode=1)

// Phase-A macros (r11 form — compiler-scheduled; manual ping-pong loses, r12).
#define PA_CROSS(P,N,C) cr[P] += ar*xr2[N].C + ai*xi2[N].C; \
                        ci[P] += ai*xr2[N].C - ar*xi2[N].C;

#define PA_G0(C) { const float rw = fmaxf(rv.C, 1e-3f); float ar, ai;          \
    ar = rw*xr2[0].C; ai = rw*xi2[0].C; d0 += ar*xr2[0].C + ai*xi2[0].C;       \
    PA_CROSS(0,1,C) PA_CROSS(1,2,C) PA_CROSS(2,3,C) PA_CROSS(3,4,C)            \
    PA_CROSS(4,5,C) PA_CROSS(5,6,C) PA_CROSS(6,7,C)                            \
    ar = rw*xr2[7].C; ai = rw*xi2[7].C; d1 += ar*xr2[7].C + ai*xi2[7].C; }

#define PA_G1(C) { const float rw = fmaxf(rv.C, 1e-3f); float ar, ai;          \
    ar = rw*xr2[1].C; ai = rw*xi2[1].C; d0 += ar*xr2[1].C + ai*xi2[1].C;       \
    PA_CROSS(0,2,C) PA_CROSS(1,3,C) PA_CROSS(2,4,C) PA_CROSS(3,5,C)            \
    PA_CROSS(4,6,C) PA_CROSS(5,7,C)                                            \
    ar = rw*xr2[6].C; ai = rw*xi2[6].C; d1 += ar*xr2[6].C + ai*xi2[6].C;       \
    PA_CROSS(6,7,C) }

#define PA_G2(C) { const float rw = fmaxf(rv.C, 1e-3f); float ar, ai;          \
    ar = rw*xr2[2].C; ai = rw*xi2[2].C; d0 += ar*xr2[2].C + ai*xi2[2].C;       \
    PA_CROSS(0,3,C) PA_CROSS(1,4,C) PA_CROSS(2,5,C) PA_CROSS(3,6,C)            \
    PA_CROSS(4,7,C)                                                            \
    ar = rw*xr2[5].C; ai = rw*xi2[5].C; d1 += ar*xr2[5].C + ai*xi2[5].C;       \
    PA_CROSS(5,6,C) PA_CROSS(6,7,C) }

#define PA_G3(C) { const float rw = fmaxf(rv.C, 1e-3f); float ar, ai;          \
    ar = rw*xr2[3].C; ai = rw*xi2[3].C; d0 += ar*xr2[3].C + ai*xi2[3].C;       \
    PA_CROSS(0,4,C) PA_CROSS(1,5,C) PA_CROSS(2,6,C) PA_CROSS(3,7,C)            \
    ar = rw*xr2[4].C; ai = rw*xi2[4].C; d1 += ar*xr2[4].C + ai*xi2[4].C;       \
    PA_CROSS(4,5,C) PA_CROSS(5,6,C) PA_CROSS(6,7,C) }

#define VSTD2(D,M)  s_V[k][M][M] = make_float2((D)*invT, 0.f);
#define VSTO2(P,M,N){ const float vr=cr[P]*invT, vi=ci[P]*invT;  \
                      s_V[k][M][N] = make_float2(vr,  vi);       \
                      s_V[k][N][M] = make_float2(vr, -vi); }

// launch_bounds law (empirical): VGPR cap = 256/arg2.
// r14 measured natural VGPR = 56 at cap 85 -> (256,4) cap 64 STILL >= 56 (no
// spill possible) while guaranteeing 4+ blocks/CU. Rounds 4/7 failed because
// their live sets (~96-150) exceeded the 64 cap; this kernel's doesn't.
__global__ __launch_bounds__(256, 4) void iss_cov(
    const float* __restrict__ g_r,
    const float* __restrict__ g_xre,
    const float* __restrict__ g_xim,
    const float* __restrict__ g_Qre,
    const float* __restrict__ g_Qim,
    float* __restrict__ g_out,
    const int qmode)
{
    __shared__ float2 s_V[8][8][9];    // padded row stride
    __shared__ float2 s_Q[8][8];

    const int tid = threadIdx.x;
    const int bf  = blockIdx.x;
    const size_t base = (size_t)bf * 4096;

    const float* xre = g_xre + base;
    const float* xim = g_xim + base;

    if (tid < 64)
        s_Q[tid>>3][tid&7] = make_float2(g_Qre[(size_t)bf*64 + tid],
                                         g_Qim[(size_t)bf*64 + tid]);

    // ---- phase A: V[k] = (1/T) sum_t max(r,1e-3) x x^H -------------------
    const int tl = tid & 7;
    const int k  = (tid >> 3) & 7;
    const int g  = tid >> 6;          // wave index, uniform

    float d0 = 0.f, d1 = 0.f;
    float cr[7], ci[7];
    #pragma unroll
    for (int p = 0; p < 7; ++p) { cr[p] = 0.f; ci[p] = 0.f; }

    {
        const float* rrow = g_r + base + (k << 9);
        #pragma unroll 4
        for (int i = 0; i < 32; ++i) {
            const int t = (i << 4) + (tl << 1);
            const float2 rv = *(const float2*)&rrow[t];
            float2 xr2[8], xi2[8];
            #pragma unroll
            for (int n = 0; n < 8; ++n) {
                xr2[n] = *(const float2*)&xre[(n << 9) + t];
                xi2[n] = *(const float2*)&xim[(n << 9) + t];
            }
            if      (g == 0) { PA_G0(x) PA_G0(y) }
            else if (g == 1) { PA_G1(x) PA_G1(y) }
            else if (g == 2) { PA_G2(x) PA_G2(y) }
            else             { PA_G3(x) PA_G3(y) }
        }
    }

    // reduce across the 8 t-lanes of each (g,k): xor 1,2,4 stay in-group
    #pragma unroll
    for (int off = 1; off < 8; off <<= 1) {
        d0 += __shfl_xor(d0, off, 64);
        d1 += __shfl_xor(d1, off, 64);
        #pragma unroll
        for (int p = 0; p < 7; ++p) {
            cr[p] += __shfl_xor(cr[p], off, 64);
            ci[p] += __shfl_xor(ci[p], off, 64);
        }
    }

    if (tl == 0) {
        const float invT = 1.0f / 512.0f;
        if (g == 0) {
            VSTD2(d0,0) VSTO2(0,0,1) VSTO2(1,0,2) VSTO2(2,0,3) VSTO2(3,0,4)
                        VSTO2(4,0,5) VSTO2(5,0,6) VSTO2(6,0,7)
            VSTD2(d1,7)
        } else if (g == 1) {
            VSTD2(d0,1) VSTO2(0,1,2) VSTO2(1,1,3) VSTO2(2,1,4) VSTO2(3,1,5)
                        VSTO2(4,1,6) VSTO2(5,1,7)
            VSTD2(d1,6) VSTO2(6,6,7)
        } else if (g == 2) {
            VSTD2(d0,2) VSTO2(0,2,3) VSTO2(1,2,4) VSTO2(2,2,5) VSTO2(3,2,6)
                        VSTO2(4,2,7)
            VSTD2(d1,5) VSTO2(5,5,6) VSTO2(6,5,7)
        } else {
            VSTD2(d0,3) VSTO2(0,3,4) VSTO2(1,3,5) VSTO2(2,3,6) VSTO2(3,3,7)
            VSTD2(d1,4) VSTO2(4,4,5) VSTO2(5,4,6) VSTO2(6,4,7)
        }
    }
    __syncthreads();

    // ---- diag fix + phase B: SINGLE WAVE, zero barriers (waves 1-3 exit) ----
    if (tid < 64) {
        {
            const int kq = tid >> 3, mq = tid & 7;
            const float dv = s_V[kq][mq][mq].x;
            float tr = dv;
            #pragma unroll
            for (int off = 1; off < 8; off <<= 1) tr += __shfl_xor(tr, off, 64);
            s_V[kq][mq][mq].x = dv + fmaxf(tr, 1.0f) * 1e-6f;
        }
        const int kp = tid >> 3, mm = tid & 7;
        float vRr[8], vRi[8];
        #pragma unroll
        for (int n = 0; n < 8; ++n) {
            const float2 V = s_V[kp][mm][n];
            vRr[n] = V.x; vRi[n] = V.y;
        }
        const float2 Q0 = s_Q[kp][mm];
        float qre = Q0.x, qim = Q0.y;

        #pragma unroll
        for (int step = 0; step < 16; ++step) {
            const int kk = step & 7;
            float qnr[8], qni[8];
            #pragma unroll
            for (int n = 0; n < 8; ++n) {
                qnr[n] = __shfl(qre, (kk<<3)+n, 64);
                qni[n] = __shfl(qim, (kk<<3)+n, 64);
            }
            const float qmr = __shfl(qre, (kk<<3)+mm, 64);
            const float qmi = __shfl(qim, (kk<<3)+mm, 64);

            float vqr = 0.f, vqi = 0.f;
            #pragma unroll
            for (int n = 0; n < 8; ++n) {
                vqr += vRr[n]*qnr[n] + vRi[n]*qni[n];   // V * conj(q)
                vqi += vRi[n]*qnr[n] - vRr[n]*qni[n];
            }
            float p   = qmr*vqr - qmi*vqi;              // Re(q_m * Vq_m)
            float tre = qre*vqr - qim*vqi;              // Q_own * Vq_own
            float tim = qre*vqi + qim*vqr;
            #pragma unroll
            for (int off = 1; off < 8; off <<= 1) {
                p   += __shfl_xor(p,   off, 64);
                tre += __shfl_xor(tre, off, 64);
                tim += __shfl_xor(tim, off, 64);
            }
            const float qvq = fmaxf(p, 1e-6f);
            float vr_, vi_;
            if (kp == kk) { vr_ = 1.0f - rsqrtf(qvq); vi_ = 0.f; }
            else { const float inv = 1.0f / qvq; vr_ = tre*inv; vi_ = tim*inv; }
            qre -= vr_*qmr - vi_*qmi;
            qim -= vr_*qmi + vi_*qmr;
        }

        d_Qc[(size_t)bf*64 + tid] = make_float2(qre, qim);   // full complex for iss_xt
        if (qmode == 2) {
            g_out[(size_t)bf*128 + tid*2]     = qre;
            g_out[(size_t)bf*128 + tid*2 + 1] = qim;
        } else {
            g_out[(size_t)bf*64 + tid] = qre;   // harness stores Q.real only
        }
    }
}

// iss_xt: pure streaming. 128 threads per bf; thread owns 4 consecutive t
// (float4 loads of x, float4 stores of xt, coalesced); Q from d_Qc (full complex).
__global__ void iss_xt(
    const float* __restrict__ g_xre,
    const float* __restrict__ g_xim,
    float* __restrict__ g_out,
    const int xt_off)
{
    __shared__ float2 s_Q[8][8];
    __shared__ float  sp[2];

    const int tid = threadIdx.x;
    const int bf  = blockIdx.x;
    const size_t base = (size_t)bf * 4096;
    const float* xre = g_xre + base;
    const float* xim = g_xim + base;

    if (tid < 64)
        s_Q[tid>>3][tid&7] = d_Qc[(size_t)bf*64 + tid];
    __syncthreads();

    float* out_xt = g_out + xt_off;
    const int t0 = tid << 2;               // 4 consecutive t
    float4 xr4[8], xi4[8];
    #pragma unroll
    for (int n = 0; n < 8; ++n) {
        xr4[n] = *(const float4*)&xre[(n << 9) + t0];
        xi4[n] = *(const float4*)&xim[(n << 9) + t0];
    }
    float lsum = 0.f;
    #pragma unroll
    for (int m = 0; m < 8; ++m) {
        float2 qv[8];
        #pragma unroll
        for (int n = 0; n < 8; ++n) qv[n] = s_Q[m][n];   // broadcast (free)
        float a0=0.f,b0=0.f,a1=0.f,b1=0.f,a2=0.f,b2=0.f,a3=0.f,b3=0.f;
        #pragma unroll
        for (int n = 0; n < 8; ++n) {
            const float qr = qv[n].x, qi = qv[n].y;
            a0 += qr*xr4[n].x - qi*xi4[n].x;  b0 += qr*xi4[n].x + qi*xr4[n].x;
            a1 += qr*xr4[n].y - qi*xi4[n].y;  b1 += qr*xi4[n].y + qi*xr4[n].y;
            a2 += qr*xr4[n].z - qi*xi4[n].z;  b2 += qr*xi4[n].z + qi*xr4[n].z;
            a3 += qr*xr4[n].w - qi*xi4[n].w;  b3 += qr*xi4[n].w + qi*xr4[n].w;
        }
        float4 pw;
        pw.x = a0*a0 + b0*b0;  pw.y = a1*a1 + b1*b1;
        pw.z = a2*a2 + b2*b2;  pw.w = a3*a3 + b3*b3;
        *(float4*)&out_xt[base + (m << 9) + t0] = pw;
        lsum += pw.x + pw.y + pw.z + pw.w;
    }
    #pragma unroll
    for (int off = 32; off >= 1; off >>= 1) lsum += __shfl_xor(lsum, off, 64);
    if ((tid & 63) == 0) sp[tid >> 6] = lsum;
    __syncthreads();
    if (tid == 0) d_partials[bf] = sp[0] + sp[1];
}

__global__ __launch_bounds__(256) void iss_scale()
{
    const int b = blockIdx.x, tid = threadIdx.x;
    __shared__ float sp[4];
    float s = 0.f;
    for (int i = tid; i < 513; i += 256) s += d_partials[b*513 + i];
    #pragma unroll
    for (int off = 32; off >= 1; off >>= 1) s += __shfl_xor(s, off, 64);
    if ((tid & 63) == 0) sp[tid >> 6] = s;
    __syncthreads();
    if (tid == 0) d_scales[b] = (sp[0]+sp[1]+sp[2]+sp[3]) / (513.0f * 8.0f * 512.0f);
}

__global__ __launch_bounds__(256) void iss_norm(
    float* __restrict__ g_out,
    const int nq4,     // Q region in float4s  (= xt_off/4)
    const int qb4,     // float4s per batch in Q region
    const int nt4)     // total float4s (= out_size/4)
{
    float4* o4 = (float4*)g_out;
    for (int i = blockIdx.x*256 + threadIdx.x; i < nt4; i += gridDim.x*256) {
        float s;
        if (i < nq4) {
            const int b = i / qb4;
            s = rsqrtf(fmaxf(d_scales[b], 1e-6f));
        } else {
            const int j = i - nq4;
            const int b = j / 525312;          // xt float4s per batch
            s = 1.0f / d_scales[b];
        }
        float4 v = o4[i];
        v.x *= s; v.y *= s; v.z *= s; v.w *= s;
        o4[i] = v;
    }
}

extern "C" void kernel_launch(void* const* d_in, const int* in_sizes, int n_in,
                              void* d_out, int out_size, void* d_ws, size_t ws_size,
                              hipStream_t stream) {
    const float* r   = (const float*)d_in[0];
    const float* xre = (const float*)d_in[1];
    const float* xim = (const float*)d_in[2];
    const float* Qre = (const float*)d_in[3];
    const float* Qim = (const float*)d_in[4];
    float* out = (float*)d_out;

    const int q_floats = out_size - XT_FLOATS;
    const int qmode  = (q_floats >= 525312) ? 2 : 1;  // empirically qmode=1 (r13)
    const int xt_off = (qmode == 2) ? 525312 : 262656;
    const int nq4 = xt_off / 4;
    const int qb4 = xt_off / (4 * 8);
    const int nt4 = nq4 + XT_FLOATS / 4;

    iss_cov  <<<NBF, 256, 0, stream>>>(r, xre, xim, Qre, Qim, out, qmode);
    iss_xt   <<<NBF, 128, 0, stream>>>(xre, xim, out, xt_off);
    iss_scale<<<8,   256, 0, stream>>>();
    iss_norm <<<4096,256, 0, stream>>>(out, nq4, qb4, nt4);
}

// Round 16
// 205.089 us; speedup vs baseline: 2.6117x; 1.4792x over previous
//
#include <hip/hip_runtime.h>
#include <math.h>

#define NBF 4104             // B*F = 8*513
#define XT_FLOATS 16809984   // 8*513*8*512

// Static device scratch; fully overwritten before read each call -> deterministic.
__device__ float  d_partials[NBF];
__device__ float  d_scales[8];
__device__ float2 d_Qc[NBF * 64];   // full complex Q (g_out only holds Re in qmode=1)

// Phase-A macros over float4 components (C in {x,y,z,w}).
#define PA_CROSS(P,N,C) cr[P] += ar*xr4[N].C + ai*xi4[N].C; \
                        ci[P] += ai*xr4[N].C - ar*xi4[N].C;

#define PA_G0(C) { const float rw = fmaxf(rv.C, 1e-3f); float ar, ai;          \
    ar = rw*xr4[0].C; ai = rw*xi4[0].C; d0 += ar*xr4[0].C + ai*xi4[0].C;       \
    PA_CROSS(0,1,C) PA_CROSS(1,2,C) PA_CROSS(2,3,C) PA_CROSS(3,4,C)            \
    PA_CROSS(4,5,C) PA_CROSS(5,6,C) PA_CROSS(6,7,C)                            \
    ar = rw*xr4[7].C; ai = rw*xi4[7].C; d1 += ar*xr4[7].C + ai*xi4[7].C; }

#define PA_G1(C) { const float rw = fmaxf(rv.C, 1e-3f); float ar, ai;          \
    ar = rw*xr4[1].C; ai = rw*xi4[1].C; d0 += ar*xr4[1].C + ai*xi4[1].C;       \
    PA_CROSS(0,2,C) PA_CROSS(1,3,C) PA_CROSS(2,4,C) PA_CROSS(3,5,C)            \
    PA_CROSS(4,6,C) PA_CROSS(5,7,C)                                            \
    ar = rw*xr4[6].C; ai = rw*xi4[6].C; d1 += ar*xr4[6].C + ai*xi4[6].C;       \
    PA_CROSS(6,7,C) }

#define PA_G2(C) { const float rw = fmaxf(rv.C, 1e-3f); float ar, ai;          \
    ar = rw*xr4[2].C; ai = rw*xi4[2].C; d0 += ar*xr4[2].C + ai*xi4[2].C;       \
    PA_CROSS(0,3,C) PA_CROSS(1,4,C) PA_CROSS(2,5,C) PA_CROSS(3,6,C)            \
    PA_CROSS(4,7,C)                                                            \
    ar = rw*xr4[5].C; ai = rw*xi4[5].C; d1 += ar*xr4[5].C + ai*xi4[5].C;       \
    PA_CROSS(5,6,C) PA_CROSS(6,7,C) }

#define PA_G3(C) { const float rw = fmaxf(rv.C, 1e-3f); float ar, ai;          \
    ar = rw*xr4[3].C; ai = rw*xi4[3].C; d0 += ar*xr4[3].C + ai*xi4[3].C;       \
    PA_CROSS(0,4,C) PA_CROSS(1,5,C) PA_CROSS(2,6,C) PA_CROSS(3,7,C)            \
    ar = rw*xr4[4].C; ai = rw*xi4[4].C; d1 += ar*xr4[4].C + ai*xi4[4].C;       \
    PA_CROSS(4,5,C) PA_CROSS(5,6,C) PA_CROSS(6,7,C) }

#define VSTD2(D,M)  s_V[k][M][M] = make_float2((D)*invT, 0.f);
#define VSTO2(P,M,N){ const float vr=cr[P]*invT, vi=ci[P]*invT;  \
                      s_V[k][M][N] = make_float2(vr,  vi);       \
                      s_V[k][N][M] = make_float2(vr, -vi); }

// float4 t-chunking: 272 VMEM instrs/wave (was 544), 2x compute per iteration.
// Live set ~94; cap 128 via (256,2) -> 1.36x margin, no spill (r8 lesson).
// Occupancy 22-42% proven irrelevant (r10/r11/r15) - latency/issue is the lever.
__global__ __launch_bounds__(256, 2) void iss_cov(
    const float* __restrict__ g_r,
    const float* __restrict__ g_xre,
    const float* __restrict__ g_xim,
    const float* __restrict__ g_Qre,
    const float* __restrict__ g_Qim,
    float* __restrict__ g_out,
    const int qmode)
{
    __shared__ float2 s_V[8][8][9];    // padded row stride
    __shared__ float2 s_Q[8][8];

    const int tid = threadIdx.x;
    const int bf  = blockIdx.x;
    const size_t base = (size_t)bf * 4096;

    const float* xre = g_xre + base;
    const float* xim = g_xim + base;

    if (tid < 64)
        s_Q[tid>>3][tid&7] = make_float2(g_Qre[(size_t)bf*64 + tid],
                                         g_Qim[(size_t)bf*64 + tid]);

    // ---- phase A: V[k] = (1/T) sum_t max(r,1e-3) x x^H -------------------
    // tid = (g<<6)|(k<<3)|tl : wave g owns row-pair {g,7-g}; 8 t-lanes per (g,k);
    // lane handles t = {32i + 4tl .. +3} (float4, 16B-aligned, coalesced).
    const int tl = tid & 7;
    const int k  = (tid >> 3) & 7;
    const int g  = tid >> 6;          // wave index, uniform

    float d0 = 0.f, d1 = 0.f;
    float cr[7], ci[7];
    #pragma unroll
    for (int p = 0; p < 7; ++p) { cr[p] = 0.f; ci[p] = 0.f; }

    {
        const float* rrow = g_r + base + (k << 9);
        #pragma unroll 2
        for (int i = 0; i < 16; ++i) {
            const int t = (i << 5) + (tl << 2);
            const float4 rv = *(const float4*)&rrow[t];
            float4 xr4[8], xi4[8];
            #pragma unroll
            for (int n = 0; n < 8; ++n) {
                xr4[n] = *(const float4*)&xre[(n << 9) + t];
                xi4[n] = *(const float4*)&xim[(n << 9) + t];
            }
            if      (g == 0) { PA_G0(x) PA_G0(y) PA_G0(z) PA_G0(w) }
            else if (g == 1) { PA_G1(x) PA_G1(y) PA_G1(z) PA_G1(w) }
            else if (g == 2) { PA_G2(x) PA_G2(y) PA_G2(z) PA_G2(w) }
            else             { PA_G3(x) PA_G3(y) PA_G3(z) PA_G3(w) }
        }
    }

    // reduce across the 8 t-lanes of each (g,k): xor 1,2,4 stay in-group
    #pragma unroll
    for (int off = 1; off < 8; off <<= 1) {
        d0 += __shfl_xor(d0, off, 64);
        d1 += __shfl_xor(d1, off, 64);
        #pragma unroll
        for (int p = 0; p < 7; ++p) {
            cr[p] += __shfl_xor(cr[p], off, 64);
            ci[p] += __shfl_xor(ci[p], off, 64);
        }
    }

    if (tl == 0) {
        const float invT = 1.0f / 512.0f;
        if (g == 0) {
            VSTD2(d0,0) VSTO2(0,0,1) VSTO2(1,0,2) VSTO2(2,0,3) VSTO2(3,0,4)
                        VSTO2(4,0,5) VSTO2(5,0,6) VSTO2(6,0,7)
            VSTD2(d1,7)
        } else if (g == 1) {
            VSTD2(d0,1) VSTO2(0,1,2) VSTO2(1,1,3) VSTO2(2,1,4) VSTO2(3,1,5)
                        VSTO2(4,1,6) VSTO2(5,1,7)
            VSTD2(d1,6) VSTO2(6,6,7)
        } else if (g == 2) {
            VSTD2(d0,2) VSTO2(0,2,3) VSTO2(1,2,4) VSTO2(2,2,5) VSTO2(3,2,6)
                        VSTO2(4,2,7)
            VSTD2(d1,5) VSTO2(5,5,6) VSTO2(6,5,7)
        } else {
            VSTD2(d0,3) VSTO2(0,3,4) VSTO2(1,3,5) VSTO2(2,3,6) VSTO2(3,3,7)
            VSTD2(d1,4) VSTO2(4,4,5) VSTO2(5,4,6) VSTO2(6,4,7)
        }
    }
    __syncthreads();

    // ---- diag fix + phase B: SINGLE WAVE, zero barriers (waves 1-3 exit) ----
    if (tid < 64) {
        {
            const int kq = tid >> 3, mq = tid & 7;
            const float dv = s_V[kq][mq][mq].x;
            float tr = dv;
            #pragma unroll
            for (int off = 1; off < 8; off <<= 1) tr += __shfl_xor(tr, off, 64);
            s_V[kq][mq][mq].x = dv + fmaxf(tr, 1.0f) * 1e-6f;
        }
        const int kp = tid >> 3, mm = tid & 7;
        float vRr[8], vRi[8];
        #pragma unroll
        for (int n = 0; n < 8; ++n) {
            const float2 V = s_V[kp][mm][n];
            vRr[n] = V.x; vRi[n] = V.y;
        }
        const float2 Q0 = s_Q[kp][mm];
        float qre = Q0.x, qim = Q0.y;

        #pragma unroll
        for (int step = 0; step < 16; ++step) {
            const int kk = step & 7;
            float qnr[8], qni[8];
            #pragma unroll
            for (int n = 0; n < 8; ++n) {
                qnr[n] = __shfl(qre, (kk<<3)+n, 64);
                qni[n] = __shfl(qim, (kk<<3)+n, 64);
            }
            const float qmr = __shfl(qre, (kk<<3)+mm, 64);
            const float qmi = __shfl(qim, (kk<<3)+mm, 64);

            float vqr = 0.f, vqi = 0.f;
            #pragma unroll
            for (int n = 0; n < 8; ++n) {
                vqr += vRr[n]*qnr[n] + vRi[n]*qni[n];   // V * conj(q)
                vqi += vRi[n]*qnr[n] - vRr[n]*qni[n];
            }
            float p   = qmr*vqr - qmi*vqi;              // Re(q_m * Vq_m)
            float tre = qre*vqr - qim*vqi;              // Q_own * Vq_own
            float tim = qre*vqi + qim*vqr;
            #pragma unroll
            for (int off = 1; off < 8; off <<= 1) {
                p   += __shfl_xor(p,   off, 64);
                tre += __shfl_xor(tre, off, 64);
                tim += __shfl_xor(tim, off, 64);
            }
            const float qvq = fmaxf(p, 1e-6f);
            float vr_, vi_;
            if (kp == kk) { vr_ = 1.0f - rsqrtf(qvq); vi_ = 0.f; }
            else { const float inv = 1.0f / qvq; vr_ = tre*inv; vi_ = tim*inv; }
            qre -= vr_*qmr - vi_*qmi;
            qim -= vr_*qmi + vi_*qmr;
        }

        d_Qc[(size_t)bf*64 + tid] = make_float2(qre, qim);   // full complex for iss_xt
        if (qmode == 2) {
            g_out[(size_t)bf*128 + tid*2]     = qre;
            g_out[(size_t)bf*128 + tid*2 + 1] = qim;
        } else {
            g_out[(size_t)bf*64 + tid] = qre;   // harness stores Q.real only
        }
    }
}

// iss_xt: pure streaming. 128 threads per bf; thread owns 4 consecutive t
// (float4 loads of x, float4 stores of xt, coalesced); Q from d_Qc (full complex).
__global__ void iss_xt(
    const float* __restrict__ g_xre,
    const float* __restrict__ g_xim,
    float* __restrict__ g_out,
    const int xt_off)
{
    __shared__ float2 s_Q[8][8];
    __shared__ float  sp[2];

    const int tid = threadIdx.x;
    const int bf  = blockIdx.x;
    const size_t base = (size_t)bf * 4096;
    const float* xre = g_xre + base;
    const float* xim = g_xim + base;

    if (tid < 64)
        s_Q[tid>>3][tid&7] = d_Qc[(size_t)bf*64 + tid];
    __syncthreads();

    float* out_xt = g_out + xt_off;
    const int t0 = tid << 2;               // 4 consecutive t
    float4 xr4[8], xi4[8];
    #pragma unroll
    for (int n = 0; n < 8; ++n) {
        xr4[n] = *(const float4*)&xre[(n << 9) + t0];
        xi4[n] = *(const float4*)&xim[(n << 9) + t0];
    }
    float lsum = 0.f;
    #pragma unroll
    for (int m = 0; m < 8; ++m) {
        float2 qv[8];
        #pragma unroll
        for (int n = 0; n < 8; ++n) qv[n] = s_Q[m][n];   // broadcast (free)
        float a0=0.f,b0=0.f,a1=0.f,b1=0.f,a2=0.f,b2=0.f,a3=0.f,b3=0.f;
        #pragma unroll
        for (int n = 0; n < 8; ++n) {
            const float qr = qv[n].x, qi = qv[n].y;
            a0 += qr*xr4[n].x - qi*xi4[n].x;  b0 += qr*xi4[n].x + qi*xr4[n].x;
            a1 += qr*xr4[n].y - qi*xi4[n].y;  b1 += qr*xi4[n].y + qi*xr4[n].y;
            a2 += qr*xr4[n].z - qi*xi4[n].z;  b2 += qr*xi4[n].z + qi*xr4[n].z;
            a3 += qr*xr4[n].w - qi*xi4[n].w;  b3 += qr*xi4[n].w + qi*xr4[n].w;
        }
        float4 pw;
        pw.x = a0*a0 + b0*b0;  pw.y = a1*a1 + b1*b1;
        pw.z = a2*a2 + b2*b2;  pw.w = a3*a3 + b3*b3;
        *(float4*)&out_xt[base + (m << 9) + t0] = pw;
        lsum += pw.x + pw.y + pw.z + pw.w;
    }
    #pragma unroll
    for (int off = 32; off >= 1; off >>= 1) lsum += __shfl_xor(lsum, off, 64);
    if ((tid & 63) == 0) sp[tid >> 6] = lsum;
    __syncthreads();
    if (tid == 0) d_partials[bf] = sp[0] + sp[1];
}

__global__ __launch_bounds__(256) void iss_scale()
{
    const int b = blockIdx.x, tid = threadIdx.x;
    __shared__ float sp[4];
    float s = 0.f;
    for (int i = tid; i < 513; i += 256) s += d_partials[b*513 + i];
    #pragma unroll
    for (int off = 32; off >= 1; off >>= 1) s += __shfl_xor(s, off, 64);
    if ((tid & 63) == 0) sp[tid >> 6] = s;
    __syncthreads();
    if (tid == 0) d_scales[b] = (sp[0]+sp[1]+sp[2]+sp[3]) / (513.0f * 8.0f * 512.0f);
}

__global__ __launch_bounds__(256) void iss_norm(
    float* __restrict__ g_out,
    const int nq4,     // Q region in float4s  (= xt_off/4)
    const int qb4,     // float4s per batch in Q region
    const int nt4)     // total float4s (= out_size/4)
{
    float4* o4 = (float4*)g_out;
    for (int i = blockIdx.x*256 + threadIdx.x; i < nt4; i += gridDim.x*256) {
        float s;
        if (i < nq4) {
            const int b = i / qb4;
            s = rsqrtf(fmaxf(d_scales[b], 1e-6f));
        } else {
            const int j = i - nq4;
            const int b = j / 525312;          // xt float4s per batch
            s = 1.0f / d_scales[b];
        }
        float4 v = o4[i];
        v.x *= s; v.y *= s; v.z *= s; v.w *= s;
        o4[i] = v;
    }
}

extern "C" void kernel_launch(void* const* d_in, const int* in_sizes, int n_in,
                              void* d_out, int out_size, void* d_ws, size_t ws_size,
                              hipStream_t stream) {
    const float* r   = (const float*)d_in[0];
    const float* xre = (const float*)d_in[1];
    const float* xim = (const float*)d_in[2];
    const float* Qre = (const float*)d_in[3];
    const float* Qim = (const float*)d_in[4];
    float* out = (float*)d_out;

    const int q_floats = out_size - XT_FLOATS;
    const int qmode  = (q_floats >= 525312) ? 2 : 1;  // empirically qmode=1 (r13)
    const int xt_off = (qmode == 2) ? 525312 : 262656;
    const int nq4 = xt_off / 4;
    const int qb4 = xt_off / (4 * 8);
    const int nt4 = nq4 + XT_FLOATS / 4;

    iss_cov  <<<NBF, 256, 0, stream>>>(r, xre, xim, Qre, Qim, out, qmode);
    iss_xt   <<<NBF, 128, 0, stream>>>(xre, xim, out, xt_off);
    iss_scale<<<8,   256, 0, stream>>>();
    iss_norm <<<4096,256, 0, stream>>>(out, nq4, qb4, nt4);
}

// Round 17
// 193.710 us; speedup vs baseline: 2.7651x; 1.0587x over previous
//
#include <hip/hip_runtime.h>
#include <math.h>

#define NBF 4104             // B*F = 8*513
#define XT_FLOATS 16809984   // 8*513*8*512

// Static device scratch; fully overwritten before read each call -> deterministic.
__device__ float  d_partials[NBF];
__device__ float  d_scales[8];
__device__ float2 d_Qc[NBF * 64];   // full complex Q (g_out only holds Re in qmode=1)

// Phase-A macros over float4 components (C in {x,y,z,w}).
#define PA_CROSS(P,N,C) cr[P] += ar*xr4[N].C + ai*xi4[N].C; \
                        ci[P] += ai*xr4[N].C - ar*xi4[N].C;

#define PA_G0(C) { const float rw = fmaxf(rv.C, 1e-3f); float ar, ai;          \
    ar = rw*xr4[0].C; ai = rw*xi4[0].C; d0 += ar*xr4[0].C + ai*xi4[0].C;       \
    PA_CROSS(0,1,C) PA_CROSS(1,2,C) PA_CROSS(2,3,C) PA_CROSS(3,4,C)            \
    PA_CROSS(4,5,C) PA_CROSS(5,6,C) PA_CROSS(6,7,C)                            \
    ar = rw*xr4[7].C; ai = rw*xi4[7].C; d1 += ar*xr4[7].C + ai*xi4[7].C; }

#define PA_G1(C) { const float rw = fmaxf(rv.C, 1e-3f); float ar, ai;          \
    ar = rw*xr4[1].C; ai = rw*xi4[1].C; d0 += ar*xr4[1].C + ai*xi4[1].C;       \
    PA_CROSS(0,2,C) PA_CROSS(1,3,C) PA_CROSS(2,4,C) PA_CROSS(3,5,C)            \
    PA_CROSS(4,6,C) PA_CROSS(5,7,C)                                            \
    ar = rw*xr4[6].C; ai = rw*xi4[6].C; d1 += ar*xr4[6].C + ai*xi4[6].C;       \
    PA_CROSS(6,7,C) }

#define PA_G2(C) { const float rw = fmaxf(rv.C, 1e-3f); float ar, ai;          \
    ar = rw*xr4[2].C; ai = rw*xi4[2].C; d0 += ar*xr4[2].C + ai*xi4[2].C;       \
    PA_CROSS(0,3,C) PA_CROSS(1,4,C) PA_CROSS(2,5,C) PA_CROSS(3,6,C)            \
    PA_CROSS(4,7,C)                                                            \
    ar = rw*xr4[5].C; ai = rw*xi4[5].C; d1 += ar*xr4[5].C + ai*xi4[5].C;       \
    PA_CROSS(5,6,C) PA_CROSS(6,7,C) }

#define PA_G3(C) { const float rw = fmaxf(rv.C, 1e-3f); float ar, ai;          \
    ar = rw*xr4[3].C; ai = rw*xi4[3].C; d0 += ar*xr4[3].C + ai*xi4[3].C;       \
    PA_CROSS(0,4,C) PA_CROSS(1,5,C) PA_CROSS(2,6,C) PA_CROSS(3,7,C)            \
    ar = rw*xr4[4].C; ai = rw*xi4[4].C; d1 += ar*xr4[4].C + ai*xi4[4].C;       \
    PA_CROSS(4,5,C) PA_CROSS(5,6,C) PA_CROSS(6,7,C) }

#define VSTD2(D,M)  s_V[k][M][M] = make_float2((D)*invT, 0.f);
#define VSTO2(P,M,N){ const float vr=cr[P]*invT, vi=ci[P]*invT;  \
                      s_V[k][M][N] = make_float2(vr,  vi);       \
                      s_V[k][N][M] = make_float2(vr, -vi); }

// r16 result: float4 chunking -> 201 us, VALUBusy 48%. Remaining stall = global
// load latency (all 4 waves redundantly read the same 32 KB of x from L1/L2).
// This round: stage x in LDS once per block; phase-A x loads become ds_read_b128
// (conflict-free: 8 lanes x 16B = 128B spanning all 32 banks; k-groups broadcast).
// r stays global (1 of 17 loads, compiler-hoistable, L1-broadcast across waves).
__global__ __launch_bounds__(256, 2) void iss_cov(
    const float* __restrict__ g_r,
    const float* __restrict__ g_xre,
    const float* __restrict__ g_xim,
    const float* __restrict__ g_Qre,
    const float* __restrict__ g_Qim,
    float* __restrict__ g_out,
    const int qmode)
{
    __shared__ float  s_xr[8][512];    // 16 KB
    __shared__ float  s_xi[8][512];    // 16 KB
    __shared__ float2 s_V[8][8][9];    // padded row stride
    __shared__ float2 s_Q[8][8];

    const int tid = threadIdx.x;
    const int bf  = blockIdx.x;
    const size_t base = (size_t)bf * 4096;

    const float* xre = g_xre + base;
    const float* xim = g_xim + base;

    // ---- stage x into LDS (float4 loads + b128 writes, fully coalesced) ----
    {
        const float4* xr4g = (const float4*)xre;
        const float4* xi4g = (const float4*)xim;
        float4* sxr4 = (float4*)&s_xr[0][0];
        float4* sxi4 = (float4*)&s_xi[0][0];
        #pragma unroll
        for (int i = 0; i < 4; ++i) {
            const int idx = tid + (i << 8);
            sxr4[idx] = xr4g[idx];
            sxi4[idx] = xi4g[idx];
        }
        if (tid < 64)
            s_Q[tid>>3][tid&7] = make_float2(g_Qre[(size_t)bf*64 + tid],
                                             g_Qim[(size_t)bf*64 + tid]);
    }
    __syncthreads();

    // ---- phase A: V[k] = (1/T) sum_t max(r,1e-3) x x^H -------------------
    // tid = (g<<6)|(k<<3)|tl : wave g owns row-pair {g,7-g}; 8 t-lanes per (g,k);
    // lane handles t = {32i + 4tl .. +3} (b128 LDS reads, conflict-free).
    const int tl = tid & 7;
    const int k  = (tid >> 3) & 7;
    const int g  = tid >> 6;          // wave index, uniform

    float d0 = 0.f, d1 = 0.f;
    float cr[7], ci[7];
    #pragma unroll
    for (int p = 0; p < 7; ++p) { cr[p] = 0.f; ci[p] = 0.f; }

    {
        const float* rrow = g_r + base + (k << 9);
        #pragma unroll 2
        for (int i = 0; i < 16; ++i) {
            const int t = (i << 5) + (tl << 2);
            const float4 rv = *(const float4*)&rrow[t];   // global (hoistable)
            float4 xr4[8], xi4[8];
            #pragma unroll
            for (int n = 0; n < 8; ++n) {
                xr4[n] = *(const float4*)&s_xr[n][t];
                xi4[n] = *(const float4*)&s_xi[n][t];
            }
            if      (g == 0) { PA_G0(x) PA_G0(y) PA_G0(z) PA_G0(w) }
            else if (g == 1) { PA_G1(x) PA_G1(y) PA_G1(z) PA_G1(w) }
            else if (g == 2) { PA_G2(x) PA_G2(y) PA_G2(z) PA_G2(w) }
            else             { PA_G3(x) PA_G3(y) PA_G3(z) PA_G3(w) }
        }
    }

    // reduce across the 8 t-lanes of each (g,k): xor 1,2,4 stay in-group
    #pragma unroll
    for (int off = 1; off < 8; off <<= 1) {
        d0 += __shfl_xor(d0, off, 64);
        d1 += __shfl_xor(d1, off, 64);
        #pragma unroll
        for (int p = 0; p < 7; ++p) {
            cr[p] += __shfl_xor(cr[p], off, 64);
            ci[p] += __shfl_xor(ci[p], off, 64);
        }
    }

    if (tl == 0) {
        const float invT = 1.0f / 512.0f;
        if (g == 0) {
            VSTD2(d0,0) VSTO2(0,0,1) VSTO2(1,0,2) VSTO2(2,0,3) VSTO2(3,0,4)
                        VSTO2(4,0,5) VSTO2(5,0,6) VSTO2(6,0,7)
            VSTD2(d1,7)
        } else if (g == 1) {
            VSTD2(d0,1) VSTO2(0,1,2) VSTO2(1,1,3) VSTO2(2,1,4) VSTO2(3,1,5)
                        VSTO2(4,1,6) VSTO2(5,1,7)
            VSTD2(d1,6) VSTO2(6,6,7)
        } else if (g == 2) {
            VSTD2(d0,2) VSTO2(0,2,3) VSTO2(1,2,4) VSTO2(2,2,5) VSTO2(3,2,6)
                        VSTO2(4,2,7)
            VSTD2(d1,5) VSTO2(5,5,6) VSTO2(6,5,7)
        } else {
            VSTD2(d0,3) VSTO2(0,3,4) VSTO2(1,3,5) VSTO2(2,3,6) VSTO2(3,3,7)
            VSTD2(d1,4) VSTO2(4,4,5) VSTO2(5,4,6) VSTO2(6,4,7)
        }
    }
    __syncthreads();

    // ---- diag fix + phase B: SINGLE WAVE, zero barriers (waves 1-3 exit) ----
    if (tid < 64) {
        {
            const int kq = tid >> 3, mq = tid & 7;
            const float dv = s_V[kq][mq][mq].x;
            float tr = dv;
            #pragma unroll
            for (int off = 1; off < 8; off <<= 1) tr += __shfl_xor(tr, off, 64);
            s_V[kq][mq][mq].x = dv + fmaxf(tr, 1.0f) * 1e-6f;
        }
        const int kp = tid >> 3, mm = tid & 7;
        float vRr[8], vRi[8];
        #pragma unroll
        for (int n = 0; n < 8; ++n) {
            const float2 V = s_V[kp][mm][n];
            vRr[n] = V.x; vRi[n] = V.y;
        }
        const float2 Q0 = s_Q[kp][mm];
        float qre = Q0.x, qim = Q0.y;

        #pragma unroll
        for (int step = 0; step < 16; ++step) {
            const int kk = step & 7;
            float qnr[8], qni[8];
            #pragma unroll
            for (int n = 0; n < 8; ++n) {
                qnr[n] = __shfl(qre, (kk<<3)+n, 64);
                qni[n] = __shfl(qim, (kk<<3)+n, 64);
            }
            const float qmr = __shfl(qre, (kk<<3)+mm, 64);
            const float qmi = __shfl(qim, (kk<<3)+mm, 64);

            float vqr = 0.f, vqi = 0.f;
            #pragma unroll
            for (int n = 0; n < 8; ++n) {
                vqr += vRr[n]*qnr[n] + vRi[n]*qni[n];   // V * conj(q)
                vqi += vRi[n]*qnr[n] - vRr[n]*qni[n];
            }
            float p   = qmr*vqr - qmi*vqi;              // Re(q_m * Vq_m)
            float tre = qre*vqr - qim*vqi;              // Q_own * Vq_own
            float tim = qre*vqi + qim*vqr;
            #pragma unroll
            for (int off = 1; off < 8; off <<= 1) {
                p   += __shfl_xor(p,   off, 64);
                tre += __shfl_xor(tre, off, 64);
                tim += __shfl_xor(tim, off, 64);
            }
            const float qvq = fmaxf(p, 1e-6f);
            float vr_, vi_;
            if (kp == kk) { vr_ = 1.0f - rsqrtf(qvq); vi_ = 0.f; }
            else { const float inv = 1.0f / qvq; vr_ = tre*inv; vi_ = tim*inv; }
            qre -= vr_*qmr - vi_*qmi;
            qim -= vr_*qmi + vi_*qmr;
        }

        d_Qc[(size_t)bf*64 + tid] = make_float2(qre, qim);   // full complex for iss_xt
        if (qmode == 2) {
            g_out[(size_t)bf*128 + tid*2]     = qre;
            g_out[(size_t)bf*128 + tid*2 + 1] = qim;
        } else {
            g_out[(size_t)bf*64 + tid] = qre;   // harness stores Q.real only
        }
    }
}

// iss_xt: pure streaming. 128 threads per bf; thread owns 4 consecutive t
// (float4 loads of x, float4 stores of xt, coalesced); Q from d_Qc (full complex).
__global__ void iss_xt(
    const float* __restrict__ g_xre,
    const float* __restrict__ g_xim,
    float* __restrict__ g_out,
    const int xt_off)
{
    __shared__ float2 s_Q[8][8];
    __shared__ float  sp[2];

    const int tid = threadIdx.x;
    const int bf  = blockIdx.x;
    const size_t base = (size_t)bf * 4096;
    const float* xre = g_xre + base;
    const float* xim = g_xim + base;

    if (tid < 64)
        s_Q[tid>>3][tid&7] = d_Qc[(size_t)bf*64 + tid];
    __syncthreads();

    float* out_xt = g_out + xt_off;
    const int t0 = tid << 2;               // 4 consecutive t
    float4 xr4[8], xi4[8];
    #pragma unroll
    for (int n = 0; n < 8; ++n) {
        xr4[n] = *(const float4*)&xre[(n << 9) + t0];
        xi4[n] = *(const float4*)&xim[(n << 9) + t0];
    }
    float lsum = 0.f;
    #pragma unroll
    for (int m = 0; m < 8; ++m) {
        float2 qv[8];
        #pragma unroll
        for (int n = 0; n < 8; ++n) qv[n] = s_Q[m][n];   // broadcast (free)
        float a0=0.f,b0=0.f,a1=0.f,b1=0.f,a2=0.f,b2=0.f,a3=0.f,b3=0.f;
        #pragma unroll
        for (int n = 0; n < 8; ++n) {
            const float qr = qv[n].x, qi = qv[n].y;
            a0 += qr*xr4[n].x - qi*xi4[n].x;  b0 += qr*xi4[n].x + qi*xr4[n].x;
            a1 += qr*xr4[n].y - qi*xi4[n].y;  b1 += qr*xi4[n].y + qi*xr4[n].y;
            a2 += qr*xr4[n].z - qi*xi4[n].z;  b2 += qr*xi4[n].z + qi*xr4[n].z;
            a3 += qr*xr4[n].w - qi*xi4[n].w;  b3 += qr*xi4[n].w + qi*xr4[n].w;
        }
        float4 pw;
        pw.x = a0*a0 + b0*b0;  pw.y = a1*a1 + b1*b1;
        pw.z = a2*a2 + b2*b2;  pw.w = a3*a3 + b3*b3;
        *(float4*)&out_xt[base + (m << 9) + t0] = pw;
        lsum += pw.x + pw.y + pw.z + pw.w;
    }
    #pragma unroll
    for (int off = 32; off >= 1; off >>= 1) lsum += __shfl_xor(lsum, off, 64);
    if ((tid & 63) == 0) sp[tid >> 6] = lsum;
    __syncthreads();
    if (tid == 0) d_partials[bf] = sp[0] + sp[1];
}

__global__ __launch_bounds__(256) void iss_scale()
{
    const int b = blockIdx.x, tid = threadIdx.x;
    __shared__ float sp[4];
    float s = 0.f;
    for (int i = tid; i < 513; i += 256) s += d_partials[b*513 + i];
    #pragma unroll
    for (int off = 32; off >= 1; off >>= 1) s += __shfl_xor(s, off, 64);
    if ((tid & 63) == 0) sp[tid >> 6] = s;
    __syncthreads();
    if (tid == 0) d_scales[b] = (sp[0]+sp[1]+sp[2]+sp[3]) / (513.0f * 8.0f * 512.0f);
}

__global__ __launch_bounds__(256) void iss_norm(
    float* __restrict__ g_out,
    const int nq4,     // Q region in float4s  (= xt_off/4)
    const int qb4,     // float4s per batch in Q region
    const int nt4)     // total float4s (= out_size/4)
{
    float4* o4 = (float4*)g_out;
    for (int i = blockIdx.x*256 + threadIdx.x; i < nt4; i += gridDim.x*256) {
        float s;
        if (i < nq4) {
            const int b = i / qb4;
            s = rsqrtf(fmaxf(d_scales[b], 1e-6f));
        } else {
            const int j = i - nq4;
            const int b = j / 525312;          // xt float4s per batch
            s = 1.0f / d_scales[b];
        }
        float4 v = o4[i];
        v.x *= s; v.y *= s; v.z *= s; v.w *= s;
        o4[i] = v;
    }
}

extern "C" void kernel_launch(void* const* d_in, const int* in_sizes, int n_in,
                              void* d_out, int out_size, void* d_ws, size_t ws_size,
                              hipStream_t stream) {
    const float* r   = (const float*)d_in[0];
    const float* xre = (const float*)d_in[1];
    const float* xim = (const float*)d_in[2];
    const float* Qre = (const float*)d_in[3];
    const float* Qim = (const float*)d_in[4];
    float* out = (float*)d_out;

    const int q_floats = out_size - XT_FLOATS;
    const int qmode  = (q_floats >= 525312) ? 2 : 1;  // empirically qmode=1 (r13)
    const int xt_off = (qmode == 2) ? 525312 : 262656;
    const int nq4 = xt_off / 4;
    const int qb4 = xt_off / (4 * 8);
    const int nt4 = nq4 + XT_FLOATS / 4;

    iss_cov  <<<NBF, 256, 0, stream>>>(r, xre, xim, Qre, Qim, out, qmode);
    iss_xt   <<<NBF, 128, 0, stream>>>(xre, xim, out, xt_off);
    iss_scale<<<8,   256, 0, stream>>>();
    iss_norm <<<4096,256, 0, stream>>>(out, nq4, qb4, nt4);
}